// Round 3
// baseline (160.490 us; speedup 1.0000x reference)
//
#include <hip/hip_runtime.h>
#include <math.h>

#define NB 8
#define MSEG 16
#define PPIX (640*640)
#define PV4 (PPIX/4)        // 102400
#define GRIDX 100           // 100 blocks * 256 thr * 4 iters = 102400 exactly
#define STRIDE (GRIDX*256)  // 25600
#define DELTA_AGG 0.5f
#define DELTA_DIS 3.0f

// workspace float layout
#define OFF_CNT_K 0
#define OFF_CNT_T (NB*MSEG)            // 128
#define OFF_G     (2*NB*MSEG)          // 256 (N*M*4 floats; Gsum then finalized G in place)
#define OFF_LSUM  (6*NB*MSEG)          // 768
#define WS_FLOATS (7*NB*MSEG)          // 896

// ---------------- pass 1: segment sums by kern + histograms ----------------
// Register bins for the 4-channel sums; counts via ballot+popc (scalar pipe);
// cross-lane reduction via xor reduce-scatter (lane l ends owning value l).
__global__ __launch_bounds__(256, 2) void pass1_kernel(
    const float* __restrict__ preds, const int* __restrict__ targets,
    float* __restrict__ ws) {
  const int n = blockIdx.y;
  const int tid = threadIdx.x;
  const int lane = tid & 63, w = tid >> 6;

  const float4* __restrict__ c0 = (const float4*)(preds + ((size_t)n*6 + 2)*PPIX);
  const float4* __restrict__ c1 = (const float4*)(preds + ((size_t)n*6 + 3)*PPIX);
  const float4* __restrict__ c2 = (const float4*)(preds + ((size_t)n*6 + 4)*PPIX);
  const float4* __restrict__ c3 = (const float4*)(preds + ((size_t)n*6 + 5)*PPIX);
  const int4*  __restrict__ textv = (const int4*)(targets + (size_t)n*2*PPIX);
  const int4*  __restrict__ kernv = (const int4*)(targets + ((size_t)n*2 + 1)*PPIX);

  // vals[ch*16 + m] — statically indexed only
  float vals[64];
#pragma unroll
  for (int v = 0; v < 64; ++v) vals[v] = 0.f;
  int ckw[MSEG], ctw[MSEG];   // wave-uniform (ballot/popc) count accumulators
#pragma unroll
  for (int m = 0; m < MSEG; ++m) { ckw[m] = 0; ctw[m] = 0; }

#define PIX1(K, T, A0, A1, A2, A3)                                  \
  _Pragma("unroll")                                                 \
  for (int m = 0; m < MSEG; ++m) {                                  \
    bool pk = ((K) == m);                                           \
    ckw[m] += __popcll(__ballot(pk));                               \
    ctw[m] += __popcll(__ballot((T) == m));                         \
    float fk = pk ? 1.0f : 0.0f;                                    \
    vals[0*16+m] = fmaf(fk, (A0), vals[0*16+m]);                    \
    vals[1*16+m] = fmaf(fk, (A1), vals[1*16+m]);                    \
    vals[2*16+m] = fmaf(fk, (A2), vals[2*16+m]);                    \
    vals[3*16+m] = fmaf(fk, (A3), vals[3*16+m]);                    \
  }

  const int base = blockIdx.x*256 + tid;
#pragma unroll
  for (int it = 0; it < 4; ++it) {
    int p = base + it*STRIDE;
    int4 kk = kernv[p];
    int4 tt = textv[p];
    float4 a = c0[p], b = c1[p], c = c2[p], d = c3[p];
    PIX1(kk.x, tt.x, a.x, b.x, c.x, d.x);
    PIX1(kk.y, tt.y, a.y, b.y, c.y, d.y);
    PIX1(kk.z, tt.z, a.z, b.z, c.z, d.z);
    PIX1(kk.w, tt.w, a.w, b.w, c.w, d.w);
  }
#undef PIX1

  // xor reduce-scatter: 6 stages, value count 64->1; lane l ends with
  // sum over all 64 lanes of vals[l].
#pragma unroll
  for (int s = 0; s < 6; ++s) {
    const int dist = 32 >> s;        // also the half-size (V=64 matches 64 lanes)
    const bool hi = (lane & dist) != 0;
#pragma unroll
    for (int v = 0; v < (32 >> s); ++v) {
      float keep = hi ? vals[v + (32 >> s)] : vals[v];
      float send = hi ? vals[v] : vals[v + (32 >> s)];
      vals[v] = keep + __shfl_xor(send, dist);
    }
  }

  __shared__ float s_vals[4][64];
  __shared__ int   s_cnt[4][32];
  s_vals[w][lane] = vals[0];
  if (lane == 0) {
#pragma unroll
    for (int m = 0; m < MSEG; ++m) { s_cnt[w][m] = ckw[m]; s_cnt[w][16+m] = ctw[m]; }
  }
  __syncthreads();
  if (tid < 64) {
    float v = s_vals[0][tid] + s_vals[1][tid] + s_vals[2][tid] + s_vals[3][tid];
    int ch = tid >> 4, m = tid & 15;
    atomicAdd(&ws[OFF_G + n*64 + m*4 + ch], v);
  } else if (tid < 96) {
    int i = tid - 64;
    float v = (float)(s_cnt[0][i] + s_cnt[1][i] + s_cnt[2][i] + s_cnt[3][i]);
    if (i < 16) atomicAdd(&ws[OFF_CNT_K + n*MSEG + i], v);
    else        atomicAdd(&ws[OFF_CNT_T + n*MSEG + (i - 16)], v);
  }
}

// ------------- finalize G + discrimination loss (one block/batch) -------------
__global__ __launch_bounds__(256) void finalize_dis_kernel(
    float* __restrict__ ws, float* __restrict__ out) {
  const int n = blockIdx.x;
  const int tid = threadIdx.x;
  float* cnt_k = ws + OFF_CNT_K + n*MSEG;
  float* cnt_t = ws + OFF_CNT_T + n*MSEG;
  float* G     = ws + OFF_G     + (size_t)n*MSEG*4;

  __shared__ float s_G[MSEG][4];
  __shared__ int   s_valid[MSEG];
  __shared__ int   s_nv;
  __shared__ float red[256];

  if (tid < MSEG*4) {
    int m = tid >> 2;
    float g = G[tid] / fmaxf(cnt_k[m], 1.0f);
    s_G[m][tid & 3] = g;
    G[tid] = g;  // finalized G for pass 2
  }
  if (tid < MSEG)
    s_valid[tid] = (tid >= 1) && (cnt_k[tid] > 0.f) && (cnt_t[tid] > 0.f);
  __syncthreads();
  if (tid == 0) { int nv = 0; for (int m = 0; m < MSEG; m++) nv += s_valid[m]; s_nv = nv; }

  float lp = 0.f;
  {
    int i = tid >> 4, j = tid & 15;
    if (i != j && s_valid[i] && s_valid[j]) {
      float dx = s_G[i][0] - s_G[j][0];
      float dy = s_G[i][1] - s_G[j][1];
      float dz = s_G[i][2] - s_G[j][2];
      float dw = s_G[i][3] - s_G[j][3];
      float dist = sqrtf(dx*dx + dy*dy + dz*dz + dw*dw);
      float t = fmaxf(DELTA_DIS - dist, 0.f);
      lp = logf(t*t + 1.f);
    }
  }
  red[tid] = lp;
  __syncthreads();
  for (int s = 128; s > 0; s >>= 1) {
    if (tid < s) red[tid] += red[tid + s];
    __syncthreads();
  }
  if (tid == 0) {
    int nv = s_nv;
    float dis = 0.f;
    if (nv > 1) dis = 0.5f * red[0] / (float)(nv * (nv - 1));
    out[NB + n] = dis;
  }
}

// ---------------- pass 2: aggregation loss segment sums by text ----------------
__global__ __launch_bounds__(256, 2) void pass2_kernel(
    const float* __restrict__ preds, const int* __restrict__ targets,
    float* __restrict__ ws) {
  const int n = blockIdx.y;
  const int tid = threadIdx.x;
  const int lane = tid & 63, w = tid >> 6;

  const float4* __restrict__ c0 = (const float4*)(preds + ((size_t)n*6 + 2)*PPIX);
  const float4* __restrict__ c1 = (const float4*)(preds + ((size_t)n*6 + 3)*PPIX);
  const float4* __restrict__ c2 = (const float4*)(preds + ((size_t)n*6 + 4)*PPIX);
  const float4* __restrict__ c3 = (const float4*)(preds + ((size_t)n*6 + 5)*PPIX);
  const int4*  __restrict__ textv = (const int4*)(targets + (size_t)n*2*PPIX);

  __shared__ float4 s_G[MSEG];
  if (tid < MSEG) s_G[tid] = ((const float4*)(ws + OFF_G + (size_t)n*MSEG*4))[tid];
  __syncthreads();

  float ls[MSEG];
#pragma unroll
  for (int m = 0; m < MSEG; ++m) ls[m] = 0.f;

#define PIX2(T, A0, A1, A2, A3) do {                            \
    float4 g = s_G[(T)];                                        \
    float dx = (A0) - g.x, dy = (A1) - g.y;                     \
    float dz = (A2) - g.z, dw = (A3) - g.w;                     \
    float sq = fmaf(dx, dx, fmaf(dy, dy, fmaf(dz, dz, dw*dw))); \
    float dd = fmaxf(__fsqrt_rn(sq) - DELTA_AGG, 0.f);          \
    float l = __logf(fmaf(dd, dd, 1.f));                        \
    _Pragma("unroll")                                           \
    for (int m = 0; m < MSEG; ++m)                              \
      ls[m] += ((T) == m) ? l : 0.f;                            \
  } while (0)

  const int base = blockIdx.x*256 + tid;
#pragma unroll
  for (int it = 0; it < 4; ++it) {
    int p = base + it*STRIDE;
    int4 tt = textv[p];
    float4 a = c0[p], b = c1[p], c = c2[p], d = c3[p];
    PIX2(tt.x, a.x, b.x, c.x, d.x);
    PIX2(tt.y, a.y, b.y, c.y, d.y);
    PIX2(tt.z, a.z, b.z, c.z, d.z);
    PIX2(tt.w, a.w, b.w, c.w, d.w);
  }
#undef PIX2

  // reduce-scatter 16 values over bits 5..2, then butterfly-finish bits 1..0
#pragma unroll
  for (int s = 0; s < 4; ++s) {
    const int dist = 32 >> s;        // 32,16,8,4
    const bool hi = (lane & dist) != 0;
#pragma unroll
    for (int v = 0; v < (8 >> s); ++v) {
      float keep = hi ? ls[v + (8 >> s)] : ls[v];
      float send = hi ? ls[v] : ls[v + (8 >> s)];
      ls[v] = keep + __shfl_xor(send, dist);
    }
  }
  float t = ls[0];
  t += __shfl_xor(t, 2);
  t += __shfl_xor(t, 1);
  // every lane in a 4-lane group now holds the total for bin (lane>>2)

  __shared__ float s_red[4][MSEG];
  if ((lane & 3) == 0) s_red[w][lane >> 2] = t;
  __syncthreads();
  if (tid < MSEG)
    atomicAdd(&ws[OFF_LSUM + n*MSEG + tid],
              s_red[0][tid] + s_red[1][tid] + s_red[2][tid] + s_red[3][tid]);
}

// ---------------- finalize aggregation loss (one wave/batch) ----------------
__global__ __launch_bounds__(64) void finalize_agg_kernel(
    const float* __restrict__ ws, float* __restrict__ out) {
  const int n = blockIdx.x;
  const int tid = threadIdx.x;
  const float* cnt_k = ws + OFF_CNT_K + n*MSEG;
  const float* cnt_t = ws + OFF_CNT_T + n*MSEG;
  const float* lsum  = ws + OFF_LSUM  + n*MSEG;

  float lm = 0.f, vc = 0.f;
  if (tid >= 1 && tid < MSEG) {
    float ck = cnt_k[tid], ct = cnt_t[tid];
    if (ck > 0.f && ct > 0.f) {
      vc = 1.f;
      lm = lsum[tid] / fmaxf(ct, 1.f);
    }
  }
  for (int off = 32; off > 0; off >>= 1) {
    lm += __shfl_down(lm, off);
    vc += __shfl_down(vc, off);
  }
  if (tid == 0) {
    int nv = (int)(vc + 0.5f);
    out[n] = lm / (float)(nv > 1 ? nv : 1);
  }
}

extern "C" void kernel_launch(void* const* d_in, const int* in_sizes, int n_in,
                              void* d_out, int out_size, void* d_ws, size_t ws_size,
                              hipStream_t stream) {
  const float* preds   = (const float*)d_in[0];
  const int*   targets = (const int*)d_in[1];
  float* out = (float*)d_out;
  float* ws  = (float*)d_ws;

  hipMemsetAsync(d_ws, 0, WS_FLOATS * sizeof(float), stream);

  dim3 grid(GRIDX, NB);
  pass1_kernel<<<grid, 256, 0, stream>>>(preds, targets, ws);
  finalize_dis_kernel<<<NB, 256, 0, stream>>>(ws, out);
  pass2_kernel<<<grid, 256, 0, stream>>>(preds, targets, ws);
  finalize_agg_kernel<<<NB, 64, 0, stream>>>(ws, out);
}